// Round 1
// baseline (141.949 us; speedup 1.0000x reference)
//
#include <hip/hip_runtime.h>

#define NV 5000
#define NF 1000
#define HH 256
#define NPIX (HH*HH)
#define NCHUNK 1024            // 64 pixels per chunk
#define NGROUP 8               // face split for occupancy/balance
#define FPG (NF/NGROUP)        // 125 faces per group
#define NUNITS (NCHUNK*NGROUP) // 8192 work units

// ---------------- kernel 1: vertex transform + projection ----------------
__global__ void k_prep_vertex(const float* __restrict__ vtx,
                              const float* __restrict__ cam,
                              float* __restrict__ out,
                              unsigned* __restrict__ counter,
                              float2* __restrict__ xy) {
    int i = blockIdx.x * blockDim.x + threadIdx.x;
    if (i == 0) { out[0] = 0.0f; counter[0] = 0u; }
    if (i >= NV) return;
    float ex = cam[0], ey = cam[1], ez = cam[2];
    // z_ax = normalize(-eye)
    float zn = sqrtf(ex*ex + ey*ey + ez*ez) + 1e-8f;
    float zx = -ex/zn, zy = -ey/zn, zz = -ez/zn;
    // x_ax = normalize(cross((0,1,0), z)) = normalize((zz, 0, -zx))
    float xn = sqrtf(zz*zz + zx*zx) + 1e-8f;
    float xx = zz/xn, xy_ = 0.0f, xz = -zx/xn;
    // y_ax = cross(z, x)
    float yx = zy*xz - zz*xy_;
    float yy = zz*xx - zx*xz;
    float yz = zx*xy_ - zy*xx;
    float vx = vtx[i*3+0]-ex, vy = vtx[i*3+1]-ey, vz = vtx[i*3+2]-ez;
    float cxx = vx*xx + vy*xy_ + vz*xz;
    float cyy = vx*yx + vy*yy  + vz*yz;
    float czz = vx*zx + vy*zy  + vz*zz;
    const float w = 0.5773502691896258f;   // tan(30 deg)
    float den = czz*w + 1e-8f;
    xy[i] = make_float2(cxx/den, cyy/den);
}

// ---------------- kernel 2: per-face edge coefficients ----------------
// t_i = a*py + b*px + c  with  e_i = exp2(t_i) = exp(-d_i/SHARP)
// a = A * m, b = B * m, c = C * m,  m = -orient * log2(e)/SHARP
__global__ void k_face(const int* __restrict__ faces,
                       const float2* __restrict__ xy,
                       float4* __restrict__ a4,
                       float4* __restrict__ b4,
                       float* __restrict__ c1) {
    int f = blockIdx.x * blockDim.x + threadIdx.x;
    if (f >= NF) return;
    int i0 = faces[f*3+0], i1 = faces[f*3+1], i2 = faces[f*3+2];
    float2 p0 = xy[i0], p1 = xy[i1], p2 = xy[i2];
    float eax = p1.x-p0.x, eay = p1.y-p0.y;
    float ebx = p2.x-p0.x, eby = p2.y-p0.y;
    float cr = eax*eby - eay*ebx;
    float s = (cr > 0.0f) ? 1.0f : ((cr < 0.0f) ? -1.0f : 0.0f);
    const float m = -144.26950408889634f * s;   // -log2(e)/SHARP * orient

    float A0,B0,C0,A1,B1,C1,A2,B2,C2;
    {   // edge 0: p0 -> p1
        float ex_ = p1.x-p0.x, ey_ = p1.y-p0.y;
        float el = sqrtf(ex_*ex_+ey_*ey_) + 1e-8f;
        A0 = (ex_/el)*m; B0 = (-ey_/el)*m; C0 = ((ey_*p0.x - ex_*p0.y)/el)*m;
    }
    {   // edge 1: p1 -> p2
        float ex_ = p2.x-p1.x, ey_ = p2.y-p1.y;
        float el = sqrtf(ex_*ex_+ey_*ey_) + 1e-8f;
        A1 = (ex_/el)*m; B1 = (-ey_/el)*m; C1 = ((ey_*p1.x - ex_*p1.y)/el)*m;
    }
    {   // edge 2: p2 -> p0
        float ex_ = p0.x-p2.x, ey_ = p0.y-p2.y;
        float el = sqrtf(ex_*ex_+ey_*ey_) + 1e-8f;
        A2 = (ex_/el)*m; B2 = (-ey_/el)*m; C2 = ((ey_*p2.x - ex_*p2.y)/el)*m;
    }
    a4[f] = make_float4(A0, B0, C0, A1);
    b4[f] = make_float4(B1, C1, A2, B2);
    c1[f] = C2;
}

// ---------------- kernel 3: render (dynamic work queue) ----------------
__global__ __launch_bounds__(64) void k_render(
        const float4* __restrict__ a4,
        const float4* __restrict__ b4,
        const float*  __restrict__ c1,
        float* __restrict__ partials,
        unsigned* __restrict__ counter) {
    const int lane = threadIdx.x;
    for (;;) {
        unsigned u = 0;
        if (lane == 0) u = atomicAdd(counter, 1u);
        u = (unsigned)__builtin_amdgcn_readfirstlane((int)u);
        if (u >= NUNITS) return;
        const int chunk = (int)(u & (NCHUNK-1));
        const int g     = (int)(u >> 10);
        const int pix   = chunk*64 + lane;
        const float py = ((pix >> 8)      + 0.5f) * (2.0f/HH) - 1.0f;
        const float px = ((pix & (HH-1))  + 0.5f) * (2.0f/HH) - 1.0f;
        float acc = 0.0f;
        const int fbeg = g * FPG;
        for (int f = fbeg; f < fbeg + FPG; ++f) {
            float4 qa = a4[f];
            float4 qb = b4[f];
            float  qc = c1[f];
            float t0 = fmaf(qa.x, py, fmaf(qa.y, px, qa.z));
            float t1 = fmaf(qa.w, py, fmaf(qb.x, px, qb.y));
            float t2 = fmaf(qb.z, py, fmaf(qb.w, px, qc));
            float tmax = fmaxf(fmaxf(t0, t1), t2);
            // if every lane is > 25 (prob < 2^-25) the face contributes < 4.3e-8
            if (__any(tmax <= 25.0f)) {
                float e0 = __builtin_amdgcn_exp2f(t0);
                float e1 = __builtin_amdgcn_exp2f(t1);
                float e2 = __builtin_amdgcn_exp2f(t2);
                float P = (1.0f+e0) * (1.0f+e1) * (1.0f+e2);
                float prob = __builtin_amdgcn_rcpf(P);
                float q = fmaxf(1.0f - prob, 1e-6f);   // clip(prob, 0, 1-1e-6)
                acc += __builtin_amdgcn_logf(q);        // log2(1 - prob)
            }
        }
        partials[g * NPIX + pix] = acc;
    }
}

// ---------------- kernel 4: combine + loss reduction ----------------
__global__ __launch_bounds__(256) void k_combine(
        const float* __restrict__ partials,
        const float* __restrict__ ref,
        float* __restrict__ out) {
    int pix = blockIdx.x * 256 + threadIdx.x;
    float tot = 0.0f;
    #pragma unroll
    for (int g = 0; g < NGROUP; ++g) tot += partials[g * NPIX + pix];
    float sil = 1.0f - __builtin_amdgcn_exp2f(tot);   // 1 - exp(log_bg)
    float d = sil - ref[pix];
    float sq = d * d;
    #pragma unroll
    for (int off = 32; off > 0; off >>= 1)
        sq += __shfl_down(sq, off, 64);
    __shared__ float wsum[4];
    int wid = threadIdx.x >> 6;
    if ((threadIdx.x & 63) == 0) wsum[wid] = sq;
    __syncthreads();
    if (threadIdx.x == 0)
        atomicAdd(out, wsum[0] + wsum[1] + wsum[2] + wsum[3]);
}

extern "C" void kernel_launch(void* const* d_in, const int* in_sizes, int n_in,
                              void* d_out, int out_size, void* d_ws, size_t ws_size,
                              hipStream_t stream) {
    const float* vtx   = (const float*)d_in[0];   // (1,5000,3) f32
    const int*   faces = (const int*)  d_in[1];   // (1,1000,3) i32
    const float* cam   = (const float*)d_in[2];   // (3,) f32
    const float* ref   = (const float*)d_in[3];   // (256,256) f32
    float* out = (float*)d_out;

    char* ws = (char*)d_ws;
    unsigned* counter = (unsigned*)(ws + 0);
    float2*   xy      = (float2*)  (ws + 256);     // 40000 B
    float4*   a4      = (float4*)  (ws + 40448);   // 16000 B
    float4*   b4      = (float4*)  (ws + 56448);   // 16000 B
    float*    c1      = (float*)   (ws + 72448);   // 4000 B
    float*    part    = (float*)   (ws + 76800);   // 8*65536*4 = 2 MiB

    k_prep_vertex<<<dim3((NV+255)/256), dim3(256), 0, stream>>>(vtx, cam, out, counter, xy);
    k_face<<<dim3((NF+255)/256), dim3(256), 0, stream>>>(faces, xy, a4, b4, c1);
    k_render<<<dim3(2048), dim3(64), 0, stream>>>(a4, b4, c1, part, counter);
    k_combine<<<dim3(NPIX/256), dim3(256), 0, stream>>>(part, ref, out);
}

// Round 4
// 50.029 us; speedup vs baseline: 2.8373x; 2.8373x over previous
//
#include <hip/hip_runtime.h>

#define NV 5000
#define NF 1000
#define HH 256
#define NPIX (HH*HH)
#define NGROUP 8
#define FPG (NF/NGROUP)    // 125 faces per group
#define TCUT 25.0f         // exp2 cutoff: prob < 2^-25 -> negligible

// ---------------- kernel 1: vertex transform + projection (VERBATIM r1) ----
__global__ void k_prep_vertex(const float* __restrict__ vtx,
                              const float* __restrict__ cam,
                              float* __restrict__ out,
                              unsigned* __restrict__ counter,
                              float2* __restrict__ xy) {
    int i = blockIdx.x * blockDim.x + threadIdx.x;
    if (i == 0) { out[0] = 0.0f; counter[0] = 0u; }
    if (i >= NV) return;
    float ex = cam[0], ey = cam[1], ez = cam[2];
    // z_ax = normalize(-eye)
    float zn = sqrtf(ex*ex + ey*ey + ez*ez) + 1e-8f;
    float zx = -ex/zn, zy = -ey/zn, zz = -ez/zn;
    // x_ax = normalize(cross((0,1,0), z)) = normalize((zz, 0, -zx))
    float xn = sqrtf(zz*zz + zx*zx) + 1e-8f;
    float xx = zz/xn, xy_ = 0.0f, xz = -zx/xn;
    // y_ax = cross(z, x)
    float yx = zy*xz - zz*xy_;
    float yy = zz*xx - zx*xz;
    float yz = zx*xy_ - zy*xx;
    float vx = vtx[i*3+0]-ex, vy = vtx[i*3+1]-ey, vz = vtx[i*3+2]-ez;
    float cxx = vx*xx + vy*xy_ + vz*xz;
    float cyy = vx*yx + vy*yy  + vz*yz;
    float czz = vx*zx + vy*zy  + vz*zz;
    const float w = 0.5773502691896258f;   // tan(30 deg)
    float den = czz*w + 1e-8f;
    xy[i] = make_float2(cxx/den, cyy/den);
}

// ---------------- kernel 2: per-face edge coefficients (VERBATIM r1) -------
__global__ void k_face(const int* __restrict__ faces,
                       const float2* __restrict__ xy,
                       float4* __restrict__ a4,
                       float4* __restrict__ b4,
                       float* __restrict__ c1) {
    int f = blockIdx.x * blockDim.x + threadIdx.x;
    if (f >= NF) return;
    int i0 = faces[f*3+0], i1 = faces[f*3+1], i2 = faces[f*3+2];
    float2 p0 = xy[i0], p1 = xy[i1], p2 = xy[i2];
    float eax = p1.x-p0.x, eay = p1.y-p0.y;
    float ebx = p2.x-p0.x, eby = p2.y-p0.y;
    float cr = eax*eby - eay*ebx;
    float s = (cr > 0.0f) ? 1.0f : ((cr < 0.0f) ? -1.0f : 0.0f);
    const float m = -144.26950408889634f * s;   // -log2(e)/SHARP * orient

    float A0,B0,C0,A1,B1,C1,A2,B2,C2;
    {   // edge 0: p0 -> p1
        float ex_ = p1.x-p0.x, ey_ = p1.y-p0.y;
        float el = sqrtf(ex_*ex_+ey_*ey_) + 1e-8f;
        A0 = (ex_/el)*m; B0 = (-ey_/el)*m; C0 = ((ey_*p0.x - ex_*p0.y)/el)*m;
    }
    {   // edge 1: p1 -> p2
        float ex_ = p2.x-p1.x, ey_ = p2.y-p1.y;
        float el = sqrtf(ex_*ex_+ey_*ey_) + 1e-8f;
        A1 = (ex_/el)*m; B1 = (-ey_/el)*m; C1 = ((ey_*p1.x - ex_*p1.y)/el)*m;
    }
    {   // edge 2: p2 -> p0
        float ex_ = p0.x-p2.x, ey_ = p0.y-p2.y;
        float el = sqrtf(ex_*ex_+ey_*ey_) + 1e-8f;
        A2 = (ex_/el)*m; B2 = (-ey_/el)*m; C2 = ((ey_*p2.x - ex_*p2.y)/el)*m;
    }
    a4[f] = make_float4(A0, B0, C0, A1);
    b4[f] = make_float4(B1, C1, A2, B2);
    c1[f] = C2;
}

// ---------------- kernel 3: render (static grid + LDS coefficient stage) ---
__global__ __launch_bounds__(256) void k_render(
        const float4* __restrict__ a4,
        const float4* __restrict__ b4,
        const float*  __restrict__ c1,
        float* __restrict__ partials) {
    __shared__ float4 sa[FPG];
    __shared__ float4 sb[FPG];
    __shared__ float  sc[FPG];
    const int g = blockIdx.y;
    const int fbeg = g * FPG;
    if (threadIdx.x < FPG) {                 // 125 faces, one thread each
        sa[threadIdx.x] = a4[fbeg + threadIdx.x];
        sb[threadIdx.x] = b4[fbeg + threadIdx.x];
        sc[threadIdx.x] = c1[fbeg + threadIdx.x];
    }
    __syncthreads();
    const int pix = blockIdx.x * 256 + threadIdx.x;
    const float py = ((pix >> 8)      + 0.5f) * (2.0f/HH) - 1.0f;
    const float px = ((pix & (HH-1))  + 0.5f) * (2.0f/HH) - 1.0f;
    float acc = 0.0f;
    for (int j = 0; j < FPG; ++j) {
        float4 qa = sa[j];
        float4 qb = sb[j];
        float  qc = sc[j];
        float t0 = fmaf(qa.x, py, fmaf(qa.y, px, qa.z));
        float t1 = fmaf(qa.w, py, fmaf(qb.x, px, qb.y));
        float t2 = fmaf(qb.z, py, fmaf(qb.w, px, qc));
        float tmax = fmaxf(fmaxf(t0, t1), t2);
        if (__any(tmax <= TCUT)) {
            float e0 = __builtin_amdgcn_exp2f(t0);
            float e1 = __builtin_amdgcn_exp2f(t1);
            float e2 = __builtin_amdgcn_exp2f(t2);
            float Pm = (1.0f+e0) * (1.0f+e1) * (1.0f+e2);
            float prob = __builtin_amdgcn_rcpf(Pm);
            float q = fmaxf(1.0f - prob, 1e-6f);
            acc += __builtin_amdgcn_logf(q);      // log2(1-prob)
        }
    }
    partials[g * NPIX + pix] = acc;   // unconditional -> no zero-init needed
}

// ---------------- kernel 4: combine + loss reduction (VERBATIM r1) ----------
__global__ __launch_bounds__(256) void k_combine(
        const float* __restrict__ partials,
        const float* __restrict__ ref,
        float* __restrict__ out) {
    int pix = blockIdx.x * 256 + threadIdx.x;
    float tot = 0.0f;
    #pragma unroll
    for (int g = 0; g < NGROUP; ++g) tot += partials[g * NPIX + pix];
    float sil = 1.0f - __builtin_amdgcn_exp2f(tot);   // 1 - exp(log_bg)
    float d = sil - ref[pix];
    float sq = d * d;
    #pragma unroll
    for (int off = 32; off > 0; off >>= 1)
        sq += __shfl_down(sq, off, 64);
    __shared__ float wsum[4];
    int wid = threadIdx.x >> 6;
    if ((threadIdx.x & 63) == 0) wsum[wid] = sq;
    __syncthreads();
    if (threadIdx.x == 0)
        atomicAdd(out, wsum[0] + wsum[1] + wsum[2] + wsum[3]);
}

extern "C" void kernel_launch(void* const* d_in, const int* in_sizes, int n_in,
                              void* d_out, int out_size, void* d_ws, size_t ws_size,
                              hipStream_t stream) {
    const float* vtx   = (const float*)d_in[0];   // (1,5000,3) f32
    const int*   faces = (const int*)  d_in[1];   // (1,1000,3) i32
    const float* cam   = (const float*)d_in[2];   // (3,) f32
    const float* ref   = (const float*)d_in[3];   // (256,256) f32
    float* out = (float*)d_out;

    char* ws = (char*)d_ws;
    unsigned* counter = (unsigned*)(ws + 0);
    float2*   xy      = (float2*)  (ws + 256);     // 40000 B
    float4*   a4      = (float4*)  (ws + 40448);   // 16000 B
    float4*   b4      = (float4*)  (ws + 56448);   // 16000 B
    float*    c1      = (float*)   (ws + 72448);   // 4000 B
    float*    part    = (float*)   (ws + 76800);   // 8*65536*4 = 2 MiB

    k_prep_vertex<<<dim3((NV+255)/256),    dim3(256), 0, stream>>>(vtx, cam, out, counter, xy);
    k_face       <<<dim3((NF+255)/256),    dim3(256), 0, stream>>>(faces, xy, a4, b4, c1);
    k_render     <<<dim3(NPIX/256, NGROUP),dim3(256), 0, stream>>>(a4, b4, c1, part);
    k_combine    <<<dim3(NPIX/256),        dim3(256), 0, stream>>>(part, ref, out);
}